// Round 3
// baseline (319.872 us; speedup 1.0000x reference)
//
#include <hip/hip_runtime.h>
#include <stdint.h>

// RandomMaskSubgraphs — round 16: remove pipeline stages.
// r15 post-mortem: VALU trims + serial-scan fixes = noise; pipeline is a sum
// of per-kernel fixed costs + redundant memory round trips. Two structural cuts:
// 1) k_dedup+k_emit fused via bounded-spin grid rendezvous: 1024 blocks @
//    37.7KB LDS = exactly 4/CU*256 = all co-resident. Each block publishes
//    uniq_cnt (agent release) + increments done; spins (bounded ~1ms) for
//    done==NB; then computes its global offset and emits DIRECTLY from LDS,
//    skipping the ~42MB bucketmem writeback+re-read. Timeout => fallback to
//    old writeback path; k_emit (kept, skip-aware via emitted[b]) handles it.
//    Both paths bit-identical => co-residency is perf-only, never correctness.
// 2) k_scan_mask (1 block = 1 CU serial stage) split: popcount partials folded
//    into k_level1_deg blocks 0..39 (mask_bfs complete there), extraction in a
//    40-block k_mask_extract. Same launch count.
// k_append r13 geometry (proven optimum: NE=11/910 blocks); PRNG v0 bit-exact.

#define NN 40000
#define SAMPN (NN / 2)
#define WORDS 1250               // col bitmap words (40000/32)
#define SWORDS 40                // summary words
#define NB 1024                  // buckets (append bins == dedup blocks)
#define RPB 40                   // rows per bucket (1024*40 >= 40000)
#define CAP 8192                 // entries per bucket (mean ~5.3k)
#define CURSTRIDE 4
#define EPB 2816                 // edges per block in binned append (11*256)
#define NE (EPB / 256)           // 11 edges per thread
#define SELFPB 44                // self nodes per append block (910*44 >= 40000)
#define SCAP (3 * EPB + SELFPB)  // 8492 -> 34 KB
#define MWPB 250                 // mask words per extract block (40*250=10000)

// ---------------- Threefry-2x32 (20 rounds, JAX schedule) ----------------
__host__ __device__ __forceinline__ void tf2x32(unsigned k0, unsigned k1,
                                                unsigned x0, unsigned x1,
                                                unsigned &o0, unsigned &o1) {
  unsigned ks2 = k0 ^ k1 ^ 0x1BD11BDAu;
  x0 += k0; x1 += k1;
#define TFR(r) { x0 += x1; x1 = (x1 << (r)) | (x1 >> (32 - (r))); x1 ^= x0; }
  TFR(13) TFR(15) TFR(26) TFR(6)
  x0 += k1;  x1 += ks2 + 1u;
  TFR(17) TFR(29) TFR(16) TFR(24)
  x0 += ks2; x1 += k0 + 2u;
  TFR(13) TFR(15) TFR(26) TFR(6)
  x0 += k0;  x1 += k1 + 3u;
  TFR(17) TFR(29) TFR(16) TFR(24)
  x0 += k1;  x1 += ks2 + 4u;
  TFR(13) TFR(15) TFR(26) TFR(6)
  x0 += ks2; x1 += k0 + 5u;
#undef TFR
  o0 = x0; o1 = x1;
}

// jax.random.randint element e with pre-split subkeys k1=(a,b), k2=(c,d).
// m2 = ((65536 % span)^2) % span, precomputed by the caller (span-invariant).
__device__ __forceinline__ unsigned jrand(unsigned a, unsigned b, unsigned c,
                                          unsigned d, unsigned e, unsigned span,
                                          unsigned m2) {
  unsigned x0, x1, y0, y1;
  tf2x32(a, b, 0u, e, x0, x1);
  unsigned hi = x0 ^ x1;
  tf2x32(c, d, 0u, e, y0, y1);
  unsigned lo = y0 ^ y1;
  return ((hi % span) * m2 + (lo % span)) % span;
}

// ---------------- init / BFS ----------------
__global__ void k_zero16(uint4 *p, int n16) {
  int i = blockIdx.x * blockDim.x + threadIdx.x;
  if (i < n16) p[i] = make_uint4(0u, 0u, 0u, 0u);
}
__global__ void k_seed_samp(const int *seeds, int ns, unsigned char *cur,
                            unsigned char *mask_bfs,
                            unsigned a, unsigned b, unsigned c, unsigned d) {
  int i = blockIdx.x * blockDim.x + threadIdx.x;
  if (i < ns) { int s = seeds[i]; cur[s] = 1; mask_bfs[s] = 1; }
  if (i < SAMPN) {
    constexpr unsigned M2 =
        ((65536u % (unsigned)NN) * (65536u % (unsigned)NN)) % (unsigned)NN;
    unsigned idx = jrand(a, b, c, d, (unsigned)i, (unsigned)NN, M2);
    mask_bfs[idx] = 1;
  }
}
__global__ void k_level0(const int *rows, const int *cols, int E,
                         const unsigned char *cur, unsigned char *alive,
                         unsigned char *touched, unsigned char *mask_bfs) {
  int e = blockIdx.x * blockDim.x + threadIdx.x;
  if (e >= E) return;
  int r = rows[e], c = cols[e];
  if (cur[r] | cur[c]) {
    alive[e] = 0;
    touched[r] = 1; touched[c] = 1;
    mask_bfs[r] = 1; mask_bfs[c] = 1;
  } else alive[e] = 1;
}
// level-1 BFS + degree; blocks 0..39 also compute mask popcount partials
// (mask_bfs is complete before this kernel launches).
__global__ void k_level1_deg(const int *rows, const int *cols, int E,
                             const unsigned char *touched, unsigned char *alive,
                             int *deg, const unsigned *maskw, int *mask_part) {
  int tid = threadIdx.x;
  int e = blockIdx.x * blockDim.x + tid;
  if (e < E && alive[e]) {
    int r = rows[e];
    if (touched[r] | touched[cols[e]]) alive[e] = 0;
    else atomicAdd(&deg[r], 1);
  }
  if (blockIdx.x < 40) {
    __shared__ int red[4];
    int lane = tid & 63, wid = tid >> 6;
    int c = (tid < MWPB) ? __popc(maskw[blockIdx.x * MWPB + tid]) : 0;
    for (int d = 1; d < 64; d <<= 1) c += __shfl_xor(c, d, 64);
    if (lane == 0) red[wid] = c;
    __syncthreads();
    if (tid == 0) mask_part[blockIdx.x] = red[0] + red[1] + red[2] + red[3];
  }
}

// ---------------- mask extraction (40 blocks; replaces 1-block scan) --------
__global__ __launch_bounds__(256) void k_mask_extract(const unsigned *f,
                                                      const int *mask_part,
                                                      unsigned short *mask_idx,
                                                      int *tem_num) {
  __shared__ int wsum[4];
  __shared__ int basech;
  int b = blockIdx.x, tid = threadIdx.x, lane = tid & 63, wid = tid >> 6;
  if (wid == 0) {
    int v = (lane < 40) ? mask_part[lane] : 0;
    int x = v;
    for (int d = 1; d < 64; d <<= 1) {
      int y = __shfl_up(x, d, 64);
      if (lane >= d) x += y;
    }
    int basev = __shfl(x - v, b, 64);   // exclusive prefix at own block
    int total = __shfl(x, 39, 64);
    if (lane == 0) {
      basech = basev;
      if (b == 0) *tem_num = total;
    }
  }
  int w = b * MWPB + tid;
  unsigned u = (tid < MWPB) ? f[w] : 0u;
  int c = __popc(u);
  int x = c;
  for (int d = 1; d < 64; d <<= 1) {
    int y = __shfl_up(x, d, 64);
    if (lane >= d) x += y;
  }
  if (lane == 63) wsum[wid] = x;
  __syncthreads();
  if (wid == 0) {
    int v = (lane < 4) ? wsum[lane] : 0;
    int y = v;
    for (int d = 1; d < 4; d <<= 1) {
      int z = __shfl_up(y, d, 64);
      if (lane >= d) y += z;
    }
    if (lane < 4) wsum[lane] = y - v;
  }
  __syncthreads();
  int off = basech + wsum[wid] + (x - c);
  while (u) {
    int byte = (__ffs(u) - 1) >> 3;
    u &= u - 1;
    mask_idx[off++] = (unsigned short)(w * 4 + byte);
  }
}

// ---------------- binned append (tem + alive + self) + fused encoder ----------
__global__ __launch_bounds__(256) void k_append(
    const int *rows, const int *cols, const unsigned char *alive,
    const int *deg, const unsigned short *mask_idx, const int *tem_num,
    int *cursors, unsigned *bucketmem, float *out,
    unsigned ra, unsigned rb, unsigned rc, unsigned rd,
    unsigned ca, unsigned cb, unsigned cc, unsigned cd, int E) {
  __shared__ unsigned sorted[SCAP];     // 34 KB
  __shared__ int cnt[NB];               // 4 KB
  __shared__ unsigned short ofs[NB];    // 2 KB
  __shared__ int ntot_s;
  int tid = threadIdx.x, lane = tid & 63, wid = tid >> 6;
  int e0 = blockIdx.x * EPB;
  int i0 = blockIdx.x * SELFPB;         // self-node range
  int i1 = i0 + SELFPB; if (i1 > NN) i1 = NN;
  unsigned span = (unsigned)*tem_num;
  unsigned mtmp = 65536u % span;
  unsigned m2 = (mtmp * mtmp) % span;   // hoisted out of jrand (span-invariant)
  const unsigned NOPE = 0xFFFFFFFFu;

  unsigned tval[NE], aval[NE];

  for (int i = tid; i < NB; i += 256) cnt[i] = 0;
  __syncthreads();
  // pass A: draw + gather once, count, cache in registers; fused encoder out
#pragma unroll
  for (int k = 0; k < NE; k++) {
    int e = e0 + k * 256 + tid;
    if (e < E) {
      unsigned iR = jrand(ra, rb, rc, rd, (unsigned)e, span, m2);
      unsigned iC = jrand(ca, cb, cc, cd, (unsigned)e, span, m2);
      unsigned tr = (unsigned)mask_idx[iR], tc = (unsigned)mask_idx[iC];
      tval[k] = (tr << 16) | tc;
      atomicAdd(&cnt[tr / RPB], 1);
      atomicAdd(&cnt[tc / RPB], 1);
      int r = rows[e], c = cols[e];
      float v = 0.0f;
      if (alive[e]) {
        aval[k] = ((unsigned)r << 16) | (unsigned)c;
        atomicAdd(&cnt[(unsigned)r / RPB], 1);
        float xr = (float)deg[r] + 1e-12f;
        float xc = (float)deg[c] + 1e-12f;
        float dr = (float)(1.0 / sqrt((double)xr));
        float dc = (float)(1.0 / sqrt((double)xc));
        v = dr * dc;
      } else aval[k] = NOPE;
      out[e] = (float)r;
      out[E + e] = (float)c;
      out[2 * E + e] = v;
    } else { tval[k] = NOPE; aval[k] = NOPE; }
  }
  for (int i = i0 + tid; i < i1; i += 256) atomicAdd(&cnt[i / RPB], 1);
  __syncthreads();
  // exclusive scan of cnt[1024] by wave 0 -> ofs (ushort)
  if (wid == 0) {
    int carry = 0;
    for (int c8 = 0; c8 < NB / 64; c8++) {
      int v = cnt[c8 * 64 + lane];
      int x = v;
      for (int d = 1; d < 64; d <<= 1) {
        int y = __shfl_up(x, d, 64);
        if (lane >= d) x += y;
      }
      ofs[c8 * 64 + lane] = (unsigned short)(carry + x - v);
      carry += __shfl(x, 63, 64);
    }
    if (lane == 0) ntot_s = carry;
  }
  __syncthreads();
  for (int i = tid; i < NB; i += 256) cnt[i] = ofs[i];
  __syncthreads();
  // pass B: scatter from registers (+ self)
#pragma unroll
  for (int k = 0; k < NE; k++) {
    unsigned v = tval[k];
    if (v != NOPE) {
      unsigned tr = v >> 16, tc = v & 0xFFFFu;
      int p1 = atomicAdd(&cnt[tr / RPB], 1);
      sorted[p1] = v;
      int p2 = atomicAdd(&cnt[tc / RPB], 1);
      sorted[p2] = (tc << 16) | tr;
      unsigned a = aval[k];
      if (a != NOPE) {
        int p3 = atomicAdd(&cnt[(a >> 16) / RPB], 1);
        sorted[p3] = a;
      }
    }
  }
  for (int i = i0 + tid; i < i1; i += 256) {
    int p = atomicAdd(&cnt[i / RPB], 1);
    sorted[p] = ((unsigned)i << 16) | (unsigned)i;
  }
  __syncthreads();
  // reserve global space: one atomicAdd per bucket per block
  int ntot = ntot_s;
  for (int b = tid; b < NB; b += 256) {
    int end = (b < NB - 1) ? (int)ofs[b + 1] : ntot;
    int len = end - (int)ofs[b];
    cnt[b] = len ? atomicAdd(&cursors[b * CURSTRIDE], len) : 0;
  }
  __syncthreads();
  // coalesced flush (store local row id in high 16)
  for (int j = tid; j < ntot; j += 256) {
    unsigned item = sorted[j];
    unsigned r = item >> 16;
    unsigned b = r / RPB;
    unsigned lr = r - b * RPB;
    int idx = cnt[b] + (j - (int)ofs[b]);
    if (idx < CAP) bucketmem[b * CAP + idx] = (lr << 16) | (item & 0xFFFFu);
  }
}

// ---------------- dedup + fused emit (bounded-spin rendezvous) --------------
__global__ __launch_bounds__(256) void k_dedup(unsigned *bucketmem,
                                               const int *cursors, int *uniq_cnt,
                                               int *emitted, int *done,
                                               float *out, int E, int U) {
  int b = blockIdx.x;
  int rowbase = b * RPB;
  if (rowbase >= NN) {
    if (threadIdx.x == 0) {
      __hip_atomic_store(&uniq_cnt[b], 0, __ATOMIC_RELAXED,
                         __HIP_MEMORY_SCOPE_AGENT);
      __hip_atomic_fetch_add(done, 1, __ATOMIC_RELEASE,
                             __HIP_MEMORY_SCOPE_AGENT);
    }
    return; // emitted[b] stays 0; k_emit sees ub=0 -> no-op
  }

  __shared__ unsigned short arr[CAP];  // 16 KB
  __shared__ int cnt[RPB];
  __shared__ int rowend[RPB];
  __shared__ int curs[RPB];
  __shared__ int rowoff[RPB];
  __shared__ unsigned bm[4][WORDS];    // 20 KB wave-private bitmaps
  __shared__ unsigned sm[4][SWORDS];
  __shared__ int tot_s;
  __shared__ int okf;
  __shared__ int part4[4];

  int tid = threadIdx.x, lane = tid & 63, wid = tid >> 6;
  int n = cursors[b * CURSTRIDE]; if (n > CAP) n = CAP;
  const unsigned *src = bucketmem + (size_t)b * CAP;

  for (int i = tid; i < RPB; i += 256) cnt[i] = 0;
  __syncthreads();
  for (int j = tid; j < n; j += 256) atomicAdd(&cnt[src[j] >> 16], 1);
  __syncthreads();
  // wave0 parallel exclusive scan over RPB rows
  if (wid == 0) {
    int v = (lane < RPB) ? cnt[lane] : 0;
    int x = v;
    for (int d = 1; d < 64; d <<= 1) {
      int y = __shfl_up(x, d, 64);
      if (lane >= d) x += y;
    }
    if (lane < RPB) { curs[lane] = x - v; rowend[lane] = x; }
  }
  __syncthreads();
  for (int j = tid; j < n; j += 256) {
    unsigned v = src[j];
    int p = atomicAdd(&curs[v >> 16], 1);
    arr[p] = (unsigned short)v;
  }
  for (int w = lane; w < WORDS; w += 64) bm[wid][w] = 0u;
  if (lane < SWORDS) sm[wid][lane] = 0u;
  __syncthreads();

  for (int r = wid; r < RPB; r += 4) {
    int s1 = rowend[r], s0 = s1 - cnt[r];
    for (int j = s0 + lane; j < s1; j += 64) {
      unsigned c = arr[j];
      atomicOr(&bm[wid][c >> 5], 1u << (c & 31));
      atomicOr(&sm[wid][c >> 10], 1u << ((c >> 5) & 31));
    }
    unsigned s = (lane < SWORDS) ? sm[wid][lane] : 0u;
    int m = 0;
    unsigned t = s;
    while (t) {
      int w = (lane << 5) + (__ffs(t) - 1);
      t &= t - 1;
      m += __popc(bm[wid][w]);
    }
    int x = m;
    for (int d = 1; d < 64; d <<= 1) {
      int y = __shfl_up(x, d, 64);
      if (lane >= d) x += y;
    }
    int u = __shfl(x, 63, 64);
    int pos = s0 + (x - m);
    t = s;
    while (t) {
      int w = (lane << 5) + (__ffs(t) - 1);
      t &= t - 1;
      unsigned mm = bm[wid][w];
      bm[wid][w] = 0u;
      while (mm) {
        int bit = __ffs(mm) - 1;
        mm &= mm - 1;
        arr[pos++] = (unsigned short)((w << 5) + bit);
      }
    }
    if (lane < SWORDS) sm[wid][lane] = 0u;
    if (lane == 0) cnt[r] = u;
  }
  __syncthreads();
  // wave0 parallel exclusive scan of unique counts
  if (wid == 0) {
    int v = (lane < RPB) ? cnt[lane] : 0;
    int x = v;
    for (int d = 1; d < 64; d <<= 1) {
      int y = __shfl_up(x, d, 64);
      if (lane >= d) x += y;
    }
    if (lane < RPB) rowoff[lane] = x - v;
    if (lane == RPB - 1) tot_s = x;
  }
  __syncthreads();
  // ---- publish + bounded rendezvous ----
  if (tid == 0) {
    __hip_atomic_store(&uniq_cnt[b], tot_s, __ATOMIC_RELAXED,
                       __HIP_MEMORY_SCOPE_AGENT);
    __hip_atomic_fetch_add(done, 1, __ATOMIC_RELEASE,
                           __HIP_MEMORY_SCOPE_AGENT);
    int ok = 0;
    for (int it = 0; it < 1000; ++it) {
      if (__hip_atomic_load(done, __ATOMIC_ACQUIRE,
                            __HIP_MEMORY_SCOPE_AGENT) == NB) { ok = 1; break; }
      __builtin_amdgcn_s_sleep(32);
    }
    okf = ok;
  }
  __syncthreads();
  if (okf) {
    // fast path: emit directly from LDS; skip bucketmem round trip
    unsigned *uc = &bm[0][0];   // bm[0] is all-zero now; reuse as count cache
    for (int i = tid; i < NB; i += 256)
      uc[i] = (unsigned)__hip_atomic_load(&uniq_cnt[i], __ATOMIC_RELAXED,
                                          __HIP_MEMORY_SCOPE_AGENT);
    __syncthreads();
    int acc = 0;
    for (int i = tid; i < NB; i += 256)
      if (i < b) acc += (int)uc[i];
    for (int d = 1; d < 64; d <<= 1) acc += __shfl_xor(acc, d, 64);
    if (lane == 0) part4[wid] = acc;
    __syncthreads();
    int ob = part4[0] + part4[1] + part4[2] + part4[3];
    int base3 = 3 * E;
    for (int r = wid; r < RPB; r += 4) {
      int s0 = r ? rowend[r - 1] : 0;
      int u = cnt[r], o = ob + rowoff[r];
      float rowf = (float)(rowbase + r);
      for (int j = lane; j < u; j += 64) {
        int idx = o + j;
        if (idx < U) {
          out[base3 + idx] = rowf;
          out[base3 + U + idx] = (float)arr[s0 + j];
          out[base3 + 2 * U + idx] = 1.0f;
        }
      }
    }
    if (tid == 0) emitted[b] = 1;
  } else {
    // fallback: writeback packed uniques; k_emit will emit this block
    unsigned *dst = bucketmem + (size_t)b * CAP;
    for (int r = wid; r < RPB; r += 4) {
      int s0 = r ? rowend[r - 1] : 0;
      int u = cnt[r], o = rowoff[r];
      unsigned rowpack = (unsigned)(rowbase + r) << 16;
      for (int j = lane; j < u; j += 64)
        dst[o + j] = rowpack | (unsigned)arr[s0 + j];
    }
  }
}

// ---------------- emit (skip-aware; fallback + sentinel) ----------------
__global__ __launch_bounds__(256) void k_emit(const unsigned *bucketmem,
                                              const int *uniq_cnt,
                                              const int *emitted, float *out,
                                              int E, int U) {
  __shared__ int part[4];
  int b = blockIdx.x;
  int tid = threadIdx.x, lane = tid & 63, wid = tid >> 6;
  // ob = sum of uniq_cnt[0..b) via masked butterfly reduction
  int acc = 0;
  for (int i = tid; i < NB; i += 256)
    if (i < b) acc += uniq_cnt[i];
  for (int d = 1; d < 64; d <<= 1) acc += __shfl_xor(acc, d, 64);
  if (lane == 0) part[wid] = acc;
  __syncthreads();
  int ob = part[0] + part[1] + part[2] + part[3];
  int ucb = uniq_cnt[b];
  int ub = emitted[b] ? 0 : ucb;   // skip blocks already emitted by k_dedup
  const unsigned *src = bucketmem + (size_t)b * CAP;
  int base3 = 3 * E;
  for (int j = tid; j < ub; j += 256) {
    unsigned h = src[j];
    unsigned r = h >> 16;
    unsigned c = h & 0xFFFFu;
    int idx = ob + j;
    if (idx < U) {
      out[base3 + idx] = (float)r;
      out[base3 + U + idx] = (float)c;
      out[base3 + 2 * U + idx] = 1.0f;
    }
  }
  if (b == NB - 1 && tid == 0) {
    int C = ob + ucb;
    if (C != U) {
      int d = C - U; if (d < 0) d = -d; if (d > 60000) d = 60000;
      out[base3] = (float)(300000 + d); // sentinel (should never fire)
    }
  }
}

// ---------------- launch ----------------
extern "C" void kernel_launch(void *const *d_in, const int *in_sizes, int n_in,
                              void *d_out, int out_size, void *d_ws,
                              size_t ws_size, hipStream_t stream) {
  const int *rows = (const int *)d_in[0];
  const int *cols = (const int *)d_in[1];
  const int *seeds = (const int *)d_in[3];
  const int E = in_sizes[0];
  const int ns = in_sizes[3];
  float *out = (float *)d_out;
  const int U = (out_size - 3 * E) / 3;

  // ---- workspace carve: zeroed region first, rest after ----
  int *I = (int *)d_ws;
  int *deg = I;      I += NN;               // zeroed
  int *cursors = I;  I += NB * CURSTRIDE;   // zeroed
  int *uniq_cnt = I; I += NB;               // zeroed
  int *emitted = I;  I += NB;               // zeroed
  int *done = I;     I += 8;                // zeroed (barrier counter + pad)
  unsigned char *cur = (unsigned char *)I;  // 3*NN bytes zeroed
  unsigned char *touched = cur + NN;
  unsigned char *mask_bfs = touched + NN;
  size_t zero_bytes = (size_t)((char *)(mask_bfs + NN) - (char *)deg);
  int *J = (int *)(mask_bfs + NN);
  int *tem_num = J;  J += 1;
  J += 1; // pad to 8B
  int *mask_part = J; J += 40;              // popcount partials (fully written)
  unsigned short *mask_idx = (unsigned short *)J;
  J += NN / 2; // 40000 ushorts = 20000 ints
  unsigned *bucketmem = (unsigned *)J; J += (size_t)NB * CAP; // 32 MB
  unsigned char *alive = (unsigned char *)J; // E bytes (fully written)

  // ---- host key derivation (v0): key(1)=(0,1); split(3); randint split(2) ----
  unsigned F[3][2];
  tf2x32(0u, 1u, 0u, 0u, F[0][0], F[0][1]); // kS
  tf2x32(0u, 1u, 0u, 1u, F[1][0], F[1][1]); // kR
  tf2x32(0u, 1u, 0u, 2u, F[2][0], F[2][1]); // kC
  unsigned K[3][4];
  for (int s = 0; s < 3; s++) {
    tf2x32(F[s][0], F[s][1], 0u, 0u, K[s][0], K[s][1]); // k1 (higher bits)
    tf2x32(F[s][0], F[s][1], 0u, 1u, K[s][2], K[s][3]); // k2 (lower bits)
  }

  dim3 b(256);
  int gE = (E + 255) / 256;
  int gSS = (SAMPN + 255) / 256; // covers ns=2000 too
  int gT = (E + EPB - 1) / EPB;  // 910; also covers self nodes (910*44>=NN)
  int n16 = (int)(zero_bytes / 16);

  k_zero16<<<(n16 + 255) / 256, b, 0, stream>>>((uint4 *)deg, n16);
  k_seed_samp<<<gSS, b, 0, stream>>>(seeds, ns, cur, mask_bfs,
                                     K[0][0], K[0][1], K[0][2], K[0][3]);
  k_level0<<<gE, b, 0, stream>>>(rows, cols, E, cur, alive, touched, mask_bfs);
  k_level1_deg<<<gE, b, 0, stream>>>(rows, cols, E, touched, alive, deg,
                                     (const unsigned *)mask_bfs, mask_part);
  k_mask_extract<<<40, b, 0, stream>>>((const unsigned *)mask_bfs, mask_part,
                                       mask_idx, tem_num);
  k_append<<<gT, b, 0, stream>>>(rows, cols, alive, deg, mask_idx, tem_num,
                                 cursors, bucketmem, out,
                                 K[1][0], K[1][1], K[1][2], K[1][3],
                                 K[2][0], K[2][1], K[2][2], K[2][3], E);
  k_dedup<<<NB, b, 0, stream>>>(bucketmem, cursors, uniq_cnt, emitted, done,
                                out, E, U);
  k_emit<<<NB, b, 0, stream>>>(bucketmem, uniq_cnt, emitted, out, E, U);
}

// Round 5
// 250.455 us; speedup vs baseline: 1.2772x; 1.2772x over previous
//
#include <hip/hip_runtime.h>
#include <stdint.h>

// RandomMaskSubgraphs — round 18: resubmit r17 (container infra failure,
// no bench verdict; audit found no hang/fault mechanism).
// r17: fatter append blocks; revert r16 fusion.
// r16 post-mortem: grid-wide bounded-spin rendezvous in k_dedup cost ~50us
// (every block waits for the global straggler while holding LDS). RULE: never
// trade a kernel boundary for an intra-kernel grid sync here.
// r14 lesson: k_append is per-block-overhead bound (NB-sized cnt zero/scan/
// copy + 1024 cursor atomics + barriers). r17 halves overhead instances the
// other way: 512-thread blocks, EPB 5632 (NE=11 unchanged per-thread), 455
// blocks @ ~72.4KB LDS = 2/CU x 8 waves = 16 waves/CU (same residency),
// single generation. Flush segments 8.3->18.5/bucket (less write amp).
// Also: k_zero16 shrunk to 3 byte arrays; deg/cursors zeroing folded into
// k_level0; uniq_cnt needs no zeroing (fully written by k_dedup).
// Mask pipeline: r16's 40-block extract kept (popcount partials in level1).
// PRNG v0 (partitionable split + randint subkey split) bit-exact since r4.

#define NN 40000
#define SAMPN (NN / 2)
#define WORDS 1250               // col bitmap words (40000/32)
#define SWORDS 40                // summary words
#define NB 1024                  // buckets (append bins == dedup blocks)
#define RPB 40                   // rows per bucket (1024*40 >= 40000)
#define CAP 8192                 // entries per bucket (mean ~5.3k)
#define CURSTRIDE 4
#define APPT 512                 // k_append threads per block
#define EPB 5632                 // edges per append block (11*512)
#define NE (EPB / APPT)          // 11 edges per thread
#define SELFPB 88                // self nodes per append block (455*88 >= 40000)
#define SCAP (3 * EPB + SELFPB)  // 16984 -> 67.9 KB
#define MWPB 250                 // mask words per extract block (40*250=10000)

// ---------------- Threefry-2x32 (20 rounds, JAX schedule) ----------------
__host__ __device__ __forceinline__ void tf2x32(unsigned k0, unsigned k1,
                                                unsigned x0, unsigned x1,
                                                unsigned &o0, unsigned &o1) {
  unsigned ks2 = k0 ^ k1 ^ 0x1BD11BDAu;
  x0 += k0; x1 += k1;
#define TFR(r) { x0 += x1; x1 = (x1 << (r)) | (x1 >> (32 - (r))); x1 ^= x0; }
  TFR(13) TFR(15) TFR(26) TFR(6)
  x0 += k1;  x1 += ks2 + 1u;
  TFR(17) TFR(29) TFR(16) TFR(24)
  x0 += ks2; x1 += k0 + 2u;
  TFR(13) TFR(15) TFR(26) TFR(6)
  x0 += k0;  x1 += k1 + 3u;
  TFR(17) TFR(29) TFR(16) TFR(24)
  x0 += k1;  x1 += ks2 + 4u;
  TFR(13) TFR(15) TFR(26) TFR(6)
  x0 += ks2; x1 += k0 + 5u;
#undef TFR
  o0 = x0; o1 = x1;
}

// jax.random.randint element e with pre-split subkeys k1=(a,b), k2=(c,d).
// m2 = ((65536 % span)^2) % span, precomputed by the caller (span-invariant).
__device__ __forceinline__ unsigned jrand(unsigned a, unsigned b, unsigned c,
                                          unsigned d, unsigned e, unsigned span,
                                          unsigned m2) {
  unsigned x0, x1, y0, y1;
  tf2x32(a, b, 0u, e, x0, x1);
  unsigned hi = x0 ^ x1;
  tf2x32(c, d, 0u, e, y0, y1);
  unsigned lo = y0 ^ y1;
  return ((hi % span) * m2 + (lo % span)) % span;
}

// ---------------- init / BFS ----------------
__global__ void k_zero16(uint4 *p, int n16) {
  int i = blockIdx.x * blockDim.x + threadIdx.x;
  if (i < n16) p[i] = make_uint4(0u, 0u, 0u, 0u);
}
__global__ void k_seed_samp(const int *seeds, int ns, unsigned char *cur,
                            unsigned char *mask_bfs,
                            unsigned a, unsigned b, unsigned c, unsigned d) {
  int i = blockIdx.x * blockDim.x + threadIdx.x;
  if (i < ns) { int s = seeds[i]; cur[s] = 1; mask_bfs[s] = 1; }
  if (i < SAMPN) {
    constexpr unsigned M2 =
        ((65536u % (unsigned)NN) * (65536u % (unsigned)NN)) % (unsigned)NN;
    unsigned idx = jrand(a, b, c, d, (unsigned)i, (unsigned)NN, M2);
    mask_bfs[idx] = 1;
  }
}
// level-0 BFS; also zeroes deg + cursors (used by later kernels only).
__global__ void k_level0(const int *rows, const int *cols, int E,
                         const unsigned char *cur, unsigned char *alive,
                         unsigned char *touched, unsigned char *mask_bfs,
                         int *deg, int *cursors) {
  int e = blockIdx.x * blockDim.x + threadIdx.x;
  if (e < NN) deg[e] = 0;
  int e2 = e - NN;
  if (e2 >= 0 && e2 < NB * CURSTRIDE) cursors[e2] = 0;
  if (e >= E) return;
  int r = rows[e], c = cols[e];
  if (cur[r] | cur[c]) {
    alive[e] = 0;
    touched[r] = 1; touched[c] = 1;
    mask_bfs[r] = 1; mask_bfs[c] = 1;
  } else alive[e] = 1;
}
// level-1 BFS + degree; blocks 0..39 also compute mask popcount partials
// (mask_bfs is complete before this kernel launches).
__global__ void k_level1_deg(const int *rows, const int *cols, int E,
                             const unsigned char *touched, unsigned char *alive,
                             int *deg, const unsigned *maskw, int *mask_part) {
  int tid = threadIdx.x;
  int e = blockIdx.x * blockDim.x + tid;
  if (e < E && alive[e]) {
    int r = rows[e];
    if (touched[r] | touched[cols[e]]) alive[e] = 0;
    else atomicAdd(&deg[r], 1);
  }
  if (blockIdx.x < 40) {
    __shared__ int red[4];
    int lane = tid & 63, wid = tid >> 6;
    int c = (tid < MWPB) ? __popc(maskw[blockIdx.x * MWPB + tid]) : 0;
    for (int d = 1; d < 64; d <<= 1) c += __shfl_xor(c, d, 64);
    if (lane == 0) red[wid] = c;
    __syncthreads();
    if (tid == 0) mask_part[blockIdx.x] = red[0] + red[1] + red[2] + red[3];
  }
}

// ---------------- mask extraction (40 blocks; replaces 1-block scan) --------
__global__ __launch_bounds__(256) void k_mask_extract(const unsigned *f,
                                                      const int *mask_part,
                                                      unsigned short *mask_idx,
                                                      int *tem_num) {
  __shared__ int wsum[4];
  __shared__ int basech;
  int b = blockIdx.x, tid = threadIdx.x, lane = tid & 63, wid = tid >> 6;
  if (wid == 0) {
    int v = (lane < 40) ? mask_part[lane] : 0;
    int x = v;
    for (int d = 1; d < 64; d <<= 1) {
      int y = __shfl_up(x, d, 64);
      if (lane >= d) x += y;
    }
    int basev = __shfl(x - v, b, 64);   // exclusive prefix at own block
    int total = __shfl(x, 39, 64);
    if (lane == 0) {
      basech = basev;
      if (b == 0) *tem_num = total;
    }
  }
  int w = b * MWPB + tid;
  unsigned u = (tid < MWPB) ? f[w] : 0u;
  int c = __popc(u);
  int x = c;
  for (int d = 1; d < 64; d <<= 1) {
    int y = __shfl_up(x, d, 64);
    if (lane >= d) x += y;
  }
  if (lane == 63) wsum[wid] = x;
  __syncthreads();
  if (wid == 0) {
    int v = (lane < 4) ? wsum[lane] : 0;
    int y = v;
    for (int d = 1; d < 4; d <<= 1) {
      int z = __shfl_up(y, d, 64);
      if (lane >= d) y += z;
    }
    if (lane < 4) wsum[lane] = y - v;
  }
  __syncthreads();
  int off = basech + wsum[wid] + (x - c);
  while (u) {
    int byte = (__ffs(u) - 1) >> 3;
    u &= u - 1;
    mask_idx[off++] = (unsigned short)(w * 4 + byte);
  }
}

// ---------------- binned append (tem + alive + self) + fused encoder ----------
__global__ __launch_bounds__(APPT) void k_append(
    const int *rows, const int *cols, const unsigned char *alive,
    const int *deg, const unsigned short *mask_idx, const int *tem_num,
    int *cursors, unsigned *bucketmem, float *out,
    unsigned ra, unsigned rb, unsigned rc, unsigned rd,
    unsigned ca, unsigned cb, unsigned cc, unsigned cd, int E) {
  __shared__ unsigned sorted[SCAP];     // 67.9 KB
  __shared__ int cnt[NB];               // 4 KB
  __shared__ unsigned short ofs[NB];    // 2 KB
  __shared__ int ntot_s;
  int tid = threadIdx.x, lane = tid & 63, wid = tid >> 6;
  int e0 = blockIdx.x * EPB;
  int i0 = blockIdx.x * SELFPB;         // self-node range
  int i1 = i0 + SELFPB; if (i1 > NN) i1 = NN;
  unsigned span = (unsigned)*tem_num;
  unsigned mtmp = 65536u % span;
  unsigned m2 = (mtmp * mtmp) % span;   // hoisted out of jrand (span-invariant)
  const unsigned NOPE = 0xFFFFFFFFu;

  unsigned tval[NE], aval[NE];

  for (int i = tid; i < NB; i += APPT) cnt[i] = 0;
  __syncthreads();
  // pass A: draw + gather once, count, cache in registers; fused encoder out
#pragma unroll
  for (int k = 0; k < NE; k++) {
    int e = e0 + k * APPT + tid;
    if (e < E) {
      unsigned iR = jrand(ra, rb, rc, rd, (unsigned)e, span, m2);
      unsigned iC = jrand(ca, cb, cc, cd, (unsigned)e, span, m2);
      unsigned tr = (unsigned)mask_idx[iR], tc = (unsigned)mask_idx[iC];
      tval[k] = (tr << 16) | tc;
      atomicAdd(&cnt[tr / RPB], 1);
      atomicAdd(&cnt[tc / RPB], 1);
      int r = rows[e], c = cols[e];
      float v = 0.0f;
      if (alive[e]) {
        aval[k] = ((unsigned)r << 16) | (unsigned)c;
        atomicAdd(&cnt[(unsigned)r / RPB], 1);
        float xr = (float)deg[r] + 1e-12f;
        float xc = (float)deg[c] + 1e-12f;
        float dr = (float)(1.0 / sqrt((double)xr));
        float dc = (float)(1.0 / sqrt((double)xc));
        v = dr * dc;
      } else aval[k] = NOPE;
      out[e] = (float)r;
      out[E + e] = (float)c;
      out[2 * E + e] = v;
    } else { tval[k] = NOPE; aval[k] = NOPE; }
  }
  for (int i = i0 + tid; i < i1; i += APPT) atomicAdd(&cnt[i / RPB], 1);
  __syncthreads();
  // exclusive scan of cnt[1024] by wave 0 -> ofs (ushort)
  if (wid == 0) {
    int carry = 0;
    for (int c8 = 0; c8 < NB / 64; c8++) {
      int v = cnt[c8 * 64 + lane];
      int x = v;
      for (int d = 1; d < 64; d <<= 1) {
        int y = __shfl_up(x, d, 64);
        if (lane >= d) x += y;
      }
      ofs[c8 * 64 + lane] = (unsigned short)(carry + x - v);
      carry += __shfl(x, 63, 64);
    }
    if (lane == 0) ntot_s = carry;
  }
  __syncthreads();
  for (int i = tid; i < NB; i += APPT) cnt[i] = ofs[i];
  __syncthreads();
  // pass B: scatter from registers (+ self)
#pragma unroll
  for (int k = 0; k < NE; k++) {
    unsigned v = tval[k];
    if (v != NOPE) {
      unsigned tr = v >> 16, tc = v & 0xFFFFu;
      int p1 = atomicAdd(&cnt[tr / RPB], 1);
      sorted[p1] = v;
      int p2 = atomicAdd(&cnt[tc / RPB], 1);
      sorted[p2] = (tc << 16) | tr;
      unsigned a = aval[k];
      if (a != NOPE) {
        int p3 = atomicAdd(&cnt[(a >> 16) / RPB], 1);
        sorted[p3] = a;
      }
    }
  }
  for (int i = i0 + tid; i < i1; i += APPT) {
    int p = atomicAdd(&cnt[i / RPB], 1);
    sorted[p] = ((unsigned)i << 16) | (unsigned)i;
  }
  __syncthreads();
  // reserve global space: one atomicAdd per bucket per block
  int ntot = ntot_s;
  for (int b = tid; b < NB; b += APPT) {
    int end = (b < NB - 1) ? (int)ofs[b + 1] : ntot;
    int len = end - (int)ofs[b];
    cnt[b] = len ? atomicAdd(&cursors[b * CURSTRIDE], len) : 0;
  }
  __syncthreads();
  // coalesced flush (store local row id in high 16)
  for (int j = tid; j < ntot; j += APPT) {
    unsigned item = sorted[j];
    unsigned r = item >> 16;
    unsigned b = r / RPB;
    unsigned lr = r - b * RPB;
    int idx = cnt[b] + (j - (int)ofs[b]);
    if (idx < CAP) bucketmem[b * CAP + idx] = (lr << 16) | (item & 0xFFFFu);
  }
}

// ---------------- dedup: wave-per-row + summary bitmap (single read) --------
__global__ __launch_bounds__(256) void k_dedup(unsigned *bucketmem,
                                               const int *cursors, int *uniq_cnt) {
  int b = blockIdx.x;
  int rowbase = b * RPB;
  if (rowbase >= NN) { if (threadIdx.x == 0) uniq_cnt[b] = 0; return; }

  __shared__ unsigned short arr[CAP];  // 16 KB
  __shared__ int cnt[RPB];
  __shared__ int rowend[RPB];
  __shared__ int curs[RPB];
  __shared__ int rowoff[RPB];
  __shared__ unsigned bm[4][WORDS];    // 20 KB wave-private bitmaps
  __shared__ unsigned sm[4][SWORDS];

  int tid = threadIdx.x, lane = tid & 63, wid = tid >> 6;
  int n = cursors[b * CURSTRIDE]; if (n > CAP) n = CAP;
  const unsigned *src = bucketmem + (size_t)b * CAP;

  for (int i = tid; i < RPB; i += 256) cnt[i] = 0;
  __syncthreads();
  for (int j = tid; j < n; j += 256) atomicAdd(&cnt[src[j] >> 16], 1);
  __syncthreads();
  // wave0 parallel exclusive scan over RPB rows
  if (wid == 0) {
    int v = (lane < RPB) ? cnt[lane] : 0;
    int x = v;
    for (int d = 1; d < 64; d <<= 1) {
      int y = __shfl_up(x, d, 64);
      if (lane >= d) x += y;
    }
    if (lane < RPB) { curs[lane] = x - v; rowend[lane] = x; }
  }
  __syncthreads();
  for (int j = tid; j < n; j += 256) {
    unsigned v = src[j];
    int p = atomicAdd(&curs[v >> 16], 1);
    arr[p] = (unsigned short)v;
  }
  for (int w = lane; w < WORDS; w += 64) bm[wid][w] = 0u;
  if (lane < SWORDS) sm[wid][lane] = 0u;
  __syncthreads();

  for (int r = wid; r < RPB; r += 4) {
    int s1 = rowend[r], s0 = s1 - cnt[r];
    for (int j = s0 + lane; j < s1; j += 64) {
      unsigned c = arr[j];
      atomicOr(&bm[wid][c >> 5], 1u << (c & 31));
      atomicOr(&sm[wid][c >> 10], 1u << ((c >> 5) & 31));
    }
    unsigned s = (lane < SWORDS) ? sm[wid][lane] : 0u;
    int m = 0;
    unsigned t = s;
    while (t) {
      int w = (lane << 5) + (__ffs(t) - 1);
      t &= t - 1;
      m += __popc(bm[wid][w]);
    }
    int x = m;
    for (int d = 1; d < 64; d <<= 1) {
      int y = __shfl_up(x, d, 64);
      if (lane >= d) x += y;
    }
    int u = __shfl(x, 63, 64);
    int pos = s0 + (x - m);
    t = s;
    while (t) {
      int w = (lane << 5) + (__ffs(t) - 1);
      t &= t - 1;
      unsigned mm = bm[wid][w];
      bm[wid][w] = 0u;
      while (mm) {
        int bit = __ffs(mm) - 1;
        mm &= mm - 1;
        arr[pos++] = (unsigned short)((w << 5) + bit);
      }
    }
    if (lane < SWORDS) sm[wid][lane] = 0u;
    if (lane == 0) cnt[r] = u;
  }
  __syncthreads();
  // wave0 parallel exclusive scan of unique counts
  if (wid == 0) {
    int v = (lane < RPB) ? cnt[lane] : 0;
    int x = v;
    for (int d = 1; d < 64; d <<= 1) {
      int y = __shfl_up(x, d, 64);
      if (lane >= d) x += y;
    }
    if (lane < RPB) rowoff[lane] = x - v;
    if (lane == RPB - 1) uniq_cnt[b] = x;
  }
  __syncthreads();
  // write uniques as packed (row<<16)|col — ascending == hash order
  unsigned *dst = bucketmem + (size_t)b * CAP;
  for (int r = wid; r < RPB; r += 4) {
    int s0 = r ? rowend[r - 1] : 0;
    int u = cnt[r], o = rowoff[r];
    unsigned rowpack = (unsigned)(rowbase + r) << 16;
    for (int j = lane; j < u; j += 64)
      dst[o + j] = rowpack | (unsigned)arr[s0 + j];
  }
}

// ---------------- emit (fused offset-reduction + diag) ----------------
__global__ __launch_bounds__(256) void k_emit(const unsigned *bucketmem,
                                              const int *uniq_cnt, float *out,
                                              int E, int U) {
  __shared__ int part[4];
  int b = blockIdx.x;
  int tid = threadIdx.x, lane = tid & 63, wid = tid >> 6;
  // ob = sum of uniq_cnt[0..b) via masked butterfly reduction
  int acc = 0;
  for (int i = tid; i < NB; i += 256)
    if (i < b) acc += uniq_cnt[i];
  for (int d = 1; d < 64; d <<= 1) acc += __shfl_xor(acc, d, 64);
  if (lane == 0) part[wid] = acc;
  __syncthreads();
  int ob = part[0] + part[1] + part[2] + part[3];
  int ub = uniq_cnt[b];
  const unsigned *src = bucketmem + (size_t)b * CAP;
  int base3 = 3 * E;
  for (int j = tid; j < ub; j += 256) {
    unsigned h = src[j];
    unsigned r = h >> 16;
    unsigned c = h & 0xFFFFu;
    int idx = ob + j;
    if (idx < U) {
      out[base3 + idx] = (float)r;
      out[base3 + U + idx] = (float)c;
      out[base3 + 2 * U + idx] = 1.0f;
    }
  }
  if (b == NB - 1 && tid == 0) {
    int C = ob + ub;
    if (C != U) {
      int d = C - U; if (d < 0) d = -d; if (d > 60000) d = 60000;
      out[base3] = (float)(300000 + d); // sentinel (should never fire)
    }
  }
}

// ---------------- launch ----------------
extern "C" void kernel_launch(void *const *d_in, const int *in_sizes, int n_in,
                              void *d_out, int out_size, void *d_ws,
                              size_t ws_size, hipStream_t stream) {
  const int *rows = (const int *)d_in[0];
  const int *cols = (const int *)d_in[1];
  const int *seeds = (const int *)d_in[3];
  const int E = in_sizes[0];
  const int ns = in_sizes[3];
  float *out = (float *)d_out;
  const int U = (out_size - 3 * E) / 3;

  // ---- workspace carve ----
  int *I = (int *)d_ws;
  int *deg = I;      I += NN;               // zeroed in k_level0
  int *cursors = I;  I += NB * CURSTRIDE;   // zeroed in k_level0
  int *uniq_cnt = I; I += NB;               // fully written by k_dedup
  unsigned char *cur = (unsigned char *)I;  // 3*NN bytes zeroed by k_zero16
  unsigned char *touched = cur + NN;
  unsigned char *mask_bfs = touched + NN;
  size_t zero_bytes = (size_t)(3 * NN);     // cur+touched+mask_bfs only
  int *J = (int *)(mask_bfs + NN);
  int *tem_num = J;  J += 1;
  J += 1; // pad to 8B
  int *mask_part = J; J += 40;              // popcount partials (fully written)
  unsigned short *mask_idx = (unsigned short *)J;
  J += NN / 2; // 40000 ushorts = 20000 ints
  unsigned *bucketmem = (unsigned *)J; J += (size_t)NB * CAP; // 32 MB
  unsigned char *alive = (unsigned char *)J; // E bytes (fully written)

  // ---- host key derivation (v0): key(1)=(0,1); split(3); randint split(2) ----
  unsigned F[3][2];
  tf2x32(0u, 1u, 0u, 0u, F[0][0], F[0][1]); // kS
  tf2x32(0u, 1u, 0u, 1u, F[1][0], F[1][1]); // kR
  tf2x32(0u, 1u, 0u, 2u, F[2][0], F[2][1]); // kC
  unsigned K[3][4];
  for (int s = 0; s < 3; s++) {
    tf2x32(F[s][0], F[s][1], 0u, 0u, K[s][0], K[s][1]); // k1 (higher bits)
    tf2x32(F[s][0], F[s][1], 0u, 1u, K[s][2], K[s][3]); // k2 (lower bits)
  }

  dim3 b(256);
  int gE = (E + 255) / 256;
  int gSS = (SAMPN + 255) / 256; // covers ns=2000 too
  int gT = (E + EPB - 1) / EPB;  // 455; also covers self nodes (455*88>=NN)
  int n16 = (int)(zero_bytes / 16);

  k_zero16<<<(n16 + 255) / 256, b, 0, stream>>>((uint4 *)cur, n16);
  k_seed_samp<<<gSS, b, 0, stream>>>(seeds, ns, cur, mask_bfs,
                                     K[0][0], K[0][1], K[0][2], K[0][3]);
  k_level0<<<gE, b, 0, stream>>>(rows, cols, E, cur, alive, touched, mask_bfs,
                                 deg, cursors);
  k_level1_deg<<<gE, b, 0, stream>>>(rows, cols, E, touched, alive, deg,
                                     (const unsigned *)mask_bfs, mask_part);
  k_mask_extract<<<40, b, 0, stream>>>((const unsigned *)mask_bfs, mask_part,
                                       mask_idx, tem_num);
  k_append<<<gT, dim3(APPT), 0, stream>>>(rows, cols, alive, deg, mask_idx,
                                          tem_num, cursors, bucketmem, out,
                                          K[1][0], K[1][1], K[1][2], K[1][3],
                                          K[2][0], K[2][1], K[2][2], K[2][3], E);
  k_dedup<<<NB, b, 0, stream>>>(bucketmem, cursors, uniq_cnt);
  k_emit<<<NB, b, 0, stream>>>(bucketmem, uniq_cnt, out, E, U);
}